// Round 11
// baseline (271.765 us; speedup 1.0000x reference)
//
#include <hip/hip_runtime.h>
#include <math.h>

#define T_STEPS 1024
#define BSZ     512
#define NDIM    256
#define ODIM    10
#define NCHUNK  32
#define CHUNK   32       // T_STEPS / NCHUNK (contraction t-chunking)

// ---------------- DPP helpers (hardware-verified rounds 3/4/8/9) --------------
template<int CTRL, int RMASK>
__device__ __forceinline__ float dpp_fetch(float x, float ident) {
    return __int_as_float(__builtin_amdgcn_update_dpp(
        __float_as_int(ident), __float_as_int(x), CTRL, RMASK, 0xF, false));
}

// Single-vector scan round (fallback kernel)
#define SCAN_ROUND(CTRL, RMASK)                                   \
    {   const float Ap = dpp_fetch<CTRL, RMASK>(Ac, 1.0f);        \
        const float Bp = dpp_fetch<CTRL, RMASK>(Bc, 0.0f);        \
        Bc = fmaf(Ac, Bp, Bc);                                    \
        Ac = Ac * Ap; }

// V-vector scan round: Ac shared (A-coeffs are G-independent); B duplicated.
// All Bc[v] updates read the OLD Ac; Ac updated last.
#define SCANV(CTRL, RMASK)                                        \
    {   const float Ap = dpp_fetch<CTRL, RMASK>(Ac, 1.0f);        \
        _Pragma("unroll")                                         \
        for (int v = 0; v < V; ++v) {                             \
            const float Bp = dpp_fetch<CTRL, RMASK>(Bc[v], 0.0f); \
            Bc[v] = fmaf(Ac, Bp, Bc[v]);                          \
        }                                                         \
        Ac = Ac * Ap; }

// rcp + 1 Newton step (rel err ~2^-27)
__device__ __forceinline__ float fast_rcp(float x) {
    float r = __builtin_amdgcn_rcpf(x);
    return fmaf(r, fmaf(-x, r, 1.0f), r);
}

__device__ __forceinline__ void init_kmaps(int lane, float kp1[4], float tk2[4]) {
#pragma unroll
    for (int j = 0; j < 4; ++j) {
        const int k = 255 - (4 * lane + j);
        kp1[j] = (float)(k + 1);
        tk2[j] = (float)(2 * (2 * k + 1));
    }
}

// ---------------- phase 1: per-chunk basis propagation, V vectors/wave --------
// Wave (g, c): runs chunk c's CT backward steps on basis vectors e_{Vg..Vg+V-1}
// in G-space (G_k = q_k g_k). Lane l slot j holds k = 255-(4l+j) (scan order ==
// k descending). Per k: S' = al*S + be ; G' = e*G - rr*S with a = 1/(2t),
// d = 1/(1+a(k+1)), e = 2d-1, al = e+a*d, rr = 2a(2k+1)d, be = d*G.
// Coefficients + the Ac scan are shared across all V B-chains.
// Outputs: WcT[c][tl][i] = dt*S_full ; PT[c][k][i] = chunk-edge G_k.
template<int NCH, int V>
__global__ __launch_bounds__(64) void chunk_kernel(float* __restrict__ PT,
                                                   float* __restrict__ WcT) {
    constexpr int CT = T_STEPS / NCH;
    const int g    = blockIdx.x;   // basis group 0..NDIM/V-1
    const int c    = blockIdx.y;   // chunk 0..NCH-1
    const int lane = threadIdx.x;
    const int i0   = V * g;

    float kp1[4], tk2[4];
    init_kmaps(lane, kp1, tk2);
    float G[V][4];
#pragma unroll
    for (int v = 0; v < V; ++v)
#pragma unroll
        for (int j = 0; j < 4; ++j) {
            const int k = 255 - (4 * lane + j);
            G[v][j] = (k == i0 + v) ? 1.0f : 0.0f;
        }

    float* wrow = WcT + (size_t)c * CT * NDIM + i0;
    const int tend = (c + 1) * CT, tstart = c * CT;
    float tf = (float)tend;
#pragma unroll 2
    for (int t = tend; t > tstart; --t) {
        const float dt = fast_rcp(tf);
        const float a  = 0.5f * dt;

        float e[4], al[4], rr[4], be[V][4];
#pragma unroll
        for (int j = 0; j < 4; ++j) {
            const float denom = fmaf(a, kp1[j], 1.0f);   // 1 + a(k+1)
            const float d     = fast_rcp(denom);
            const float ad    = a * d;
            e[j]  = fmaf(2.0f, d, -1.0f);                // (1 - a(k+1))d
            al[j] = e[j] + ad;                           // (1 - ak)d
            rr[j] = ad * tk2[j];                         // 2 a(2k+1) d
#pragma unroll
            for (int v = 0; v < V; ++v) be[v][j] = d * G[v][j];
        }

        float Ac = al[0];
        float Bc[V];
#pragma unroll
        for (int v = 0; v < V; ++v) Bc[v] = be[v][0];
#pragma unroll
        for (int j = 1; j < 4; ++j) {
#pragma unroll
            for (int v = 0; v < V; ++v) Bc[v] = fmaf(al[j], Bc[v], be[v][j]);
            Ac *= al[j];
        }

        SCANV(0x111, 0xF)   // row_shr:1
        SCANV(0x112, 0xF)   // row_shr:2
        SCANV(0x114, 0xF)   // row_shr:4
        SCANV(0x118, 0xF)   // row_shr:8
        SCANV(0x142, 0xA)   // row_bcast15 -> rows 1,3
        {   // row_bcast31 -> rows 2,3 ; B-only (A unused afterwards)
#pragma unroll
            for (int v = 0; v < V; ++v) {
                const float Bp = dpp_fetch<0x143, 0xC>(Bc[v], 0.0f);
                Bc[v] = fmaf(Ac, Bp, Bc[v]);
            }
        }

        float S[V];
#pragma unroll
        for (int v = 0; v < V; ++v)
            S[v] = dpp_fetch<0x138, 0xF>(Bc[v], 0.0f);   // excl prefix (wave_shr:1)

#pragma unroll
        for (int j = 0; j < 4; ++j) {
#pragma unroll
            for (int v = 0; v < V; ++v) {
                G[v][j] = fmaf(-rr[j], S[v], e[j] * G[v][j]);
                S[v]    = fmaf(al[j], S[v], be[v][j]);
            }
        }

        if (lane == 63) {
            float* wp = wrow + (size_t)(t - tstart - 1) * NDIM;
            if constexpr (V == 4)
                *(float4*)wp = make_float4(dt * S[0], dt * S[1], dt * S[2], dt * S[3]);
            else
                *(float2*)wp = make_float2(dt * S[0], dt * S[1]);
        }
        tf -= 1.0f;
    }

    // PT[c][k][i0..i0+V-1] = chunk-edge G
#pragma unroll
    for (int j = 0; j < 4; ++j) {
        const int k = 255 - (4 * lane + j);
        float* pp = PT + ((size_t)c * NDIM + k) * NDIM + i0;
        if constexpr (V == 4)
            *(float4*)pp = make_float4(G[0][j], G[1][j], G[2][j], G[3][j]);
        else
            *(float2*)pp = make_float2(G[0][j], G[1][j]);
    }
}

// ---------------- phase 2a: sequential edge-state propagation ----------------
// Block o, 1024 threads: thread (k = tid>>2, q = tid&3) owns a quarter of the
// i-reduction. Per stage: R[c][o][:] = Gs; Gs[k] = sum_i PT[c][k][i] Gs[i].
template<int NCH>
__global__ __launch_bounds__(1024) void r_kernel(const float* __restrict__ mlp_w,
                                                 const float* __restrict__ PT,
                                                 float* __restrict__ R) {
    const int o   = blockIdx.x;    // 0..9
    const int tid = threadIdx.x;   // 0..1023
    const int k   = tid >> 2;
    const int q   = tid & 3;

    __shared__ float Gs[NDIM];
    __shared__ float red[1024];
    if (tid < NDIM)
        Gs[tid] = sqrtf(2.0f * (float)tid + 1.0f) * mlp_w[o * NDIM + tid];
    __syncthreads();

    for (int c = NCH - 1; c >= 0; --c) {
        if (tid < NDIM) R[((size_t)c * ODIM + o) * NDIM + tid] = Gs[tid];
        if (c > 0) {
            const float4* row =
                (const float4*)(PT + ((size_t)c * NDIM + k) * NDIM + q * 64);
            const float* gq = Gs + q * 64;
            float a0 = 0.f, a1 = 0.f, a2 = 0.f, a3 = 0.f;
#pragma unroll
            for (int ii = 0; ii < 16; ++ii) {
                const float4 r4 = row[ii];
                a0 = fmaf(r4.x, gq[4 * ii + 0], a0);
                a1 = fmaf(r4.y, gq[4 * ii + 1], a1);
                a2 = fmaf(r4.z, gq[4 * ii + 2], a2);
                a3 = fmaf(r4.w, gq[4 * ii + 3], a3);
            }
            red[tid] = (a0 + a1) + (a2 + a3);
            __syncthreads();
            if (tid < NDIM)
                Gs[tid] = (red[4 * tid] + red[4 * tid + 1]) +
                          (red[4 * tid + 2] + red[4 * tid + 3]);
            __syncthreads();
        }
    }
}

// ---------------- phase 2b: parallel weff emission ----------------
// weff[r][o] = dot(WcT[r][:], R[c(r)][o][:]); one wave per r, 4 waves/block.
template<int CT>
__global__ __launch_bounds__(256) void z_kernel(const float* __restrict__ WcT,
                                                const float* __restrict__ R,
                                                float* __restrict__ weff) {
    __shared__ float Rl[ODIM * NDIM];
    const int tid = threadIdx.x;
    const int r0  = blockIdx.x * 4;
    const int c   = r0 / CT;      // 4 | CT always

    for (int idx = tid; idx < ODIM * NDIM; idx += 256)
        Rl[idx] = R[(size_t)c * ODIM * NDIM + idx];
    __syncthreads();

    const int w    = tid >> 6;
    const int lane = tid & 63;
    const int r    = r0 + w;
    const float4 w4 = *(const float4*)(WcT + (size_t)r * NDIM + 4 * lane);

#pragma unroll
    for (int o = 0; o < ODIM; ++o) {
        const float* Ro = Rl + o * NDIM + 4 * lane;
        float p = fmaf(w4.x, Ro[0], fmaf(w4.y, Ro[1],
                  fmaf(w4.z, Ro[2], w4.w * Ro[3])));
#pragma unroll
        for (int m = 1; m < 64; m <<= 1) p += __shfl_xor(p, m);
        if (lane == o) weff[(size_t)r * ODIM + o] = p;
    }
}

// ---------------- fallback: single-wave sequential weff (r8/r9-verified) -----
__device__ __forceinline__ float wstep(float G[4], const float kp1[4],
                                       const float tk2[4], float tf) {
    const float dt = fast_rcp(tf);
    const float a  = 0.5f * dt;

    float e[4], al[4], rr[4], be[4];
#pragma unroll
    for (int j = 0; j < 4; ++j) {
        const float denom = fmaf(a, kp1[j], 1.0f);
        const float d     = fast_rcp(denom);
        const float ad    = a * d;
        e[j]  = fmaf(2.0f, d, -1.0f);
        al[j] = e[j] + ad;
        rr[j] = ad * tk2[j];
        be[j] = d * G[j];
    }

    float Ac = al[0], Bc = be[0];
#pragma unroll
    for (int j = 1; j < 4; ++j) { Bc = fmaf(al[j], Bc, be[j]); Ac *= al[j]; }

    SCAN_ROUND(0x111, 0xF)
    SCAN_ROUND(0x112, 0xF)
    SCAN_ROUND(0x114, 0xF)
    SCAN_ROUND(0x118, 0xF)
    SCAN_ROUND(0x142, 0xA)
    {
        const float Bp = dpp_fetch<0x143, 0xC>(Bc, 0.0f);
        Bc = fmaf(Ac, Bp, Bc);
    }

    float S = dpp_fetch<0x138, 0xF>(Bc, 0.0f);
#pragma unroll
    for (int j = 0; j < 4; ++j) {
        G[j] = fmaf(-rr[j], S, e[j] * G[j]);
        S    = fmaf(al[j], S, be[j]);
    }
    return dt * S;
}

__global__ __launch_bounds__(64) void weff_kernel(const float* __restrict__ mlp_w,
                                                  float* __restrict__ weff) {
    const int o    = blockIdx.x;
    const int lane = threadIdx.x;

    float kp1[4], tk2[4], G[4];
    init_kmaps(lane, kp1, tk2);
#pragma unroll
    for (int j = 0; j < 4; ++j) {
        const int k = 255 - (4 * lane + j);
        G[j] = sqrtf((float)(2 * k + 1)) * mlp_w[o * NDIM + k];
    }

    float tf = (float)T_STEPS;
#pragma unroll 2
    for (int t = T_STEPS; t >= 1; --t) {
        const float w = wstep(G, kp1, tk2, tf);
        if (lane == 63) weff[(t - 1) * ODIM + o] = w;
        tf -= 1.0f;
    }
}

// ---------------- contraction: out[b,o] = bias + sum_t f[t,b] weff[t,o] ------
__global__ __launch_bounds__(128) void partial_kernel(const float* __restrict__ f,
                                                      const float* __restrict__ weff,
                                                      float* __restrict__ part) {
    __shared__ float wsm[CHUNK * ODIM];
    const int tid = threadIdx.x;
    const int b   = blockIdx.x * 128 + tid;
    const int tc  = blockIdx.y;
    const int t0  = tc * CHUNK;

    for (int i = tid; i < CHUNK * ODIM; i += 128)
        wsm[i] = weff[t0 * ODIM + i];
    __syncthreads();

    float acc[ODIM];
#pragma unroll
    for (int o = 0; o < ODIM; ++o) acc[o] = 0.0f;

#pragma unroll 4
    for (int tt = 0; tt < CHUNK; ++tt) {
        const float fv = f[(t0 + tt) * BSZ + b];   // coalesced over b
#pragma unroll
        for (int o = 0; o < ODIM; ++o)
            acc[o] = fmaf(fv, wsm[tt * ODIM + o], acc[o]);
    }

#pragma unroll
    for (int o = 0; o < ODIM; ++o)
        part[(tc * BSZ + b) * ODIM + o] = acc[o];
}

__global__ __launch_bounds__(256) void reduce_kernel(const float* __restrict__ part,
                                                     const float* __restrict__ mlp_b,
                                                     float* __restrict__ out) {
    const int i = blockIdx.x * 256 + threadIdx.x;
    if (i >= BSZ * ODIM) return;
    const int o = i % ODIM;
    float s = mlp_b[o];
#pragma unroll
    for (int c = 0; c < NCHUNK; ++c) s += part[c * BSZ * ODIM + i];
    out[i] = s;
}

extern "C" void kernel_launch(void* const* d_in, const int* in_sizes, int n_in,
                              void* d_out, int out_size, void* d_ws, size_t ws_size,
                              hipStream_t stream) {
    const float* inputs = (const float*)d_in[0];  // [T=1024, B=512, 1]
    const float* mlp_w  = (const float*)d_in[1];  // [10, 256]
    const float* mlp_b  = (const float*)d_in[2];  // [10]
    float* out = (float*)d_out;                   // [512, 10]

    const size_t WcT_elems  = (size_t)T_STEPS * NDIM;         // 1 MB
    const size_t weff_elems = (size_t)T_STEPS * ODIM;
    const size_t part_elems = (size_t)NCHUNK * BSZ * ODIM;

    auto need = [&](int nch) {
        return ((size_t)nch * NDIM * NDIM + WcT_elems +
                (size_t)nch * ODIM * NDIM + weff_elems + part_elems) * sizeof(float);
    };

    if (ws_size >= need(16)) {
        constexpr int NCH = 16, V = 4, CT = T_STEPS / NCH;
        float* PT   = (float*)d_ws;
        float* WcT  = PT + (size_t)NCH * NDIM * NDIM;
        float* R    = WcT + WcT_elems;
        float* weff = R + (size_t)NCH * ODIM * NDIM;
        float* part = weff + weff_elems;
        chunk_kernel<NCH, V><<<dim3(NDIM / V, NCH), 64, 0, stream>>>(PT, WcT);
        r_kernel<NCH><<<ODIM, 1024, 0, stream>>>(mlp_w, PT, R);
        z_kernel<CT><<<T_STEPS / 4, 256, 0, stream>>>(WcT, R, weff);
        partial_kernel<<<dim3(BSZ / 128, NCHUNK), 128, 0, stream>>>(inputs, weff, part);
        reduce_kernel<<<(BSZ * ODIM + 255) / 256, 256, 0, stream>>>(part, mlp_b, out);
    } else if (ws_size >= need(8)) {
        constexpr int NCH = 8, V = 2, CT = T_STEPS / NCH;
        float* PT   = (float*)d_ws;
        float* WcT  = PT + (size_t)NCH * NDIM * NDIM;
        float* R    = WcT + WcT_elems;
        float* weff = R + (size_t)NCH * ODIM * NDIM;
        float* part = weff + weff_elems;
        chunk_kernel<NCH, V><<<dim3(NDIM / V, NCH), 64, 0, stream>>>(PT, WcT);
        r_kernel<NCH><<<ODIM, 1024, 0, stream>>>(mlp_w, PT, R);
        z_kernel<CT><<<T_STEPS / 4, 256, 0, stream>>>(WcT, R, weff);
        partial_kernel<<<dim3(BSZ / 128, NCHUNK), 128, 0, stream>>>(inputs, weff, part);
        reduce_kernel<<<(BSZ * ODIM + 255) / 256, 256, 0, stream>>>(part, mlp_b, out);
    } else {
        float* weff = (float*)d_ws;
        float* part = weff + weff_elems;
        weff_kernel<<<ODIM, 64, 0, stream>>>(mlp_w, weff);
        partial_kernel<<<dim3(BSZ / 128, NCHUNK), 128, 0, stream>>>(inputs, weff, part);
        reduce_kernel<<<(BSZ * ODIM + 255) / 256, 256, 0, stream>>>(part, mlp_b, out);
    }
}

// Round 12
// 169.500 us; speedup vs baseline: 1.6033x; 1.6033x over previous
//
#include <hip/hip_runtime.h>
#include <math.h>

#define T_STEPS 1024
#define BSZ     512
#define NDIM    256
#define ODIM    10
#define NCHUNK  32
#define CHUNK   32       // T_STEPS / NCHUNK (contraction t-chunking)

// ---------------- DPP helpers (hardware-verified rounds 3/4/8/9/11) -----------
template<int CTRL, int RMASK>
__device__ __forceinline__ float dpp_fetch(float x, float ident) {
    return __int_as_float(__builtin_amdgcn_update_dpp(
        __float_as_int(ident), __float_as_int(x), CTRL, RMASK, 0xF, false));
}

// Single-vector scan round (fallback kernel)
#define SCAN_ROUND(CTRL, RMASK)                                   \
    {   const float Ap = dpp_fetch<CTRL, RMASK>(Ac, 1.0f);        \
        const float Bp = dpp_fetch<CTRL, RMASK>(Bc, 0.0f);        \
        Bc = fmaf(Ac, Bp, Bc);                                    \
        Ac = Ac * Ap; }

// V-vector scan round: Ac shared (A-coeffs are G-independent); B duplicated.
#define SCANV(CTRL, RMASK)                                        \
    {   const float Ap = dpp_fetch<CTRL, RMASK>(Ac, 1.0f);        \
        _Pragma("unroll")                                         \
        for (int v = 0; v < V; ++v) {                             \
            const float Bp = dpp_fetch<CTRL, RMASK>(Bc[v], 0.0f); \
            Bc[v] = fmaf(Ac, Bp, Bc[v]);                          \
        }                                                         \
        Ac = Ac * Ap; }

// rcp + 1 Newton step (rel err ~2^-27)
__device__ __forceinline__ float fast_rcp(float x) {
    float r = __builtin_amdgcn_rcpf(x);
    return fmaf(r, fmaf(-x, r, 1.0f), r);
}

__device__ __forceinline__ void init_kmaps(int lane, float kp1[4], float tk2[4]) {
#pragma unroll
    for (int j = 0; j < 4; ++j) {
        const int k = 255 - (4 * lane + j);
        kp1[j] = (float)(k + 1);
        tk2[j] = (float)(2 * (2 * k + 1));
    }
}

// ---------------- phase 1: per-chunk basis propagation, V vectors/wave --------
// Wave (g, c): runs chunk c's CT backward steps on basis vectors e_{Vg..Vg+V-1}
// in G-space. Per k (descending): S' = al*S + be ; G' = e*G - rr*S with
// a = 1/(2t), d = 1/(1+a(k+1)), e = 2d-1, al = e+a*d, rr = 2a(2k+1)d, be = d*G.
// Outputs: WcT[c][tl][i] = dt*S_full ; P[c][i][k] = chunk-edge G_k
// (k-CONTIGUOUS layout so r_kernel's matvec loads coalesce — r11 lesson:
// the PT[c][k][i] layout made every r_kernel load a 64-line scatter).
template<int NCH, int V>
__global__ __launch_bounds__(64) void chunk_kernel(float* __restrict__ P,
                                                   float* __restrict__ WcT) {
    constexpr int CT = T_STEPS / NCH;
    const int g    = blockIdx.x;   // basis group 0..NDIM/V-1
    const int c    = blockIdx.y;   // chunk 0..NCH-1
    const int lane = threadIdx.x;
    const int i0   = V * g;

    float kp1[4], tk2[4];
    init_kmaps(lane, kp1, tk2);
    float G[V][4];
#pragma unroll
    for (int v = 0; v < V; ++v)
#pragma unroll
        for (int j = 0; j < 4; ++j) {
            const int k = 255 - (4 * lane + j);
            G[v][j] = (k == i0 + v) ? 1.0f : 0.0f;
        }

    float* wrow = WcT + (size_t)c * CT * NDIM + i0;
    const int tend = (c + 1) * CT, tstart = c * CT;
    float tf = (float)tend;
#pragma unroll 2
    for (int t = tend; t > tstart; --t) {
        const float dt = fast_rcp(tf);
        const float a  = 0.5f * dt;

        float e[4], al[4], rr[4], be[V][4];
#pragma unroll
        for (int j = 0; j < 4; ++j) {
            const float denom = fmaf(a, kp1[j], 1.0f);   // 1 + a(k+1)
            const float d     = fast_rcp(denom);
            const float ad    = a * d;
            e[j]  = fmaf(2.0f, d, -1.0f);                // (1 - a(k+1))d
            al[j] = e[j] + ad;                           // (1 - ak)d
            rr[j] = ad * tk2[j];                         // 2 a(2k+1) d
#pragma unroll
            for (int v = 0; v < V; ++v) be[v][j] = d * G[v][j];
        }

        float Ac = al[0];
        float Bc[V];
#pragma unroll
        for (int v = 0; v < V; ++v) Bc[v] = be[v][0];
#pragma unroll
        for (int j = 1; j < 4; ++j) {
#pragma unroll
            for (int v = 0; v < V; ++v) Bc[v] = fmaf(al[j], Bc[v], be[v][j]);
            Ac *= al[j];
        }

        SCANV(0x111, 0xF)   // row_shr:1
        SCANV(0x112, 0xF)   // row_shr:2
        SCANV(0x114, 0xF)   // row_shr:4
        SCANV(0x118, 0xF)   // row_shr:8
        SCANV(0x142, 0xA)   // row_bcast15 -> rows 1,3
        {   // row_bcast31 -> rows 2,3 ; B-only (A unused afterwards)
#pragma unroll
            for (int v = 0; v < V; ++v) {
                const float Bp = dpp_fetch<0x143, 0xC>(Bc[v], 0.0f);
                Bc[v] = fmaf(Ac, Bp, Bc[v]);
            }
        }

        float S[V];
#pragma unroll
        for (int v = 0; v < V; ++v)
            S[v] = dpp_fetch<0x138, 0xF>(Bc[v], 0.0f);   // excl prefix (wave_shr:1)

#pragma unroll
        for (int j = 0; j < 4; ++j) {
#pragma unroll
            for (int v = 0; v < V; ++v) {
                G[v][j] = fmaf(-rr[j], S[v], e[j] * G[v][j]);
                S[v]    = fmaf(al[j], S[v], be[v][j]);
            }
        }

        if (lane == 63) {
            float* wp = wrow + (size_t)(t - tstart - 1) * NDIM;
            if constexpr (V == 4)
                *(float4*)wp = make_float4(dt * S[0], dt * S[1], dt * S[2], dt * S[3]);
            else
                *(float2*)wp = make_float2(dt * S[0], dt * S[1]);
        }
        tf -= 1.0f;
    }

    // P[c][i][k] = chunk-edge G (k contiguous; 4V scalar scatter-stores per
    // lane, once per kernel — negligible vs the CT-step loop)
#pragma unroll
    for (int v = 0; v < V; ++v) {
        float* prow = P + ((size_t)c * NDIM + i0 + v) * NDIM;
#pragma unroll
        for (int j = 0; j < 4; ++j) {
            const int k = 255 - (4 * lane + j);
            prow[k] = G[v][j];
        }
    }
}

// ---------------- phase 2a: sequential edge-state propagation ----------------
// Block o, 1024 threads: tid = (q<<8)|k, q = i-quarter, k = output index.
// Per stage: R[c][o][:] = Gs; Gs[k] = sum_i P[c][i][k] Gs[i].
// Loads are k-contiguous per wave (coalesced 256B segments); Gs[i] is
// wave-uniform (LDS broadcast); red[q][k] reduce is conflict-free.
template<int NCH>
__global__ __launch_bounds__(1024) void r_kernel(const float* __restrict__ mlp_w,
                                                 const float* __restrict__ P,
                                                 float* __restrict__ R) {
    const int o   = blockIdx.x;    // 0..9
    const int tid = threadIdx.x;   // 0..1023
    const int k   = tid & 255;
    const int q   = tid >> 8;      // wave-uniform (waves 0-3:q0, 4-7:q1, ...)

    __shared__ float Gs[NDIM];
    __shared__ float red[4][NDIM];
    if (tid < NDIM)
        Gs[tid] = sqrtf(2.0f * (float)tid + 1.0f) * mlp_w[o * NDIM + tid];
    __syncthreads();

    for (int c = NCH - 1; c >= 0; --c) {
        if (tid < NDIM) R[((size_t)c * ODIM + o) * NDIM + tid] = Gs[tid];
        if (c > 0) {
            const float* Pq = P + ((size_t)c * NDIM + q * 64) * NDIM + k;
            const float* gq = Gs + q * 64;
            float a0 = 0.f, a1 = 0.f, a2 = 0.f, a3 = 0.f;
#pragma unroll 4
            for (int ii = 0; ii < 64; ii += 4) {
                a0 = fmaf(Pq[(size_t)(ii + 0) * NDIM], gq[ii + 0], a0);
                a1 = fmaf(Pq[(size_t)(ii + 1) * NDIM], gq[ii + 1], a1);
                a2 = fmaf(Pq[(size_t)(ii + 2) * NDIM], gq[ii + 2], a2);
                a3 = fmaf(Pq[(size_t)(ii + 3) * NDIM], gq[ii + 3], a3);
            }
            red[q][k] = (a0 + a1) + (a2 + a3);
            __syncthreads();
            if (tid < NDIM)
                Gs[tid] = (red[0][tid] + red[1][tid]) +
                          (red[2][tid] + red[3][tid]);
            __syncthreads();
        }
    }
}

// ---------------- phase 2b: parallel weff emission ----------------
// weff[r][o] = dot(WcT[r][:], R[c(r)][o][:]); one wave per r, 4 waves/block.
template<int CT>
__global__ __launch_bounds__(256) void z_kernel(const float* __restrict__ WcT,
                                                const float* __restrict__ R,
                                                float* __restrict__ weff) {
    __shared__ float Rl[ODIM * NDIM];
    const int tid = threadIdx.x;
    const int r0  = blockIdx.x * 4;
    const int c   = r0 / CT;      // 4 | CT always

    for (int idx = tid; idx < ODIM * NDIM; idx += 256)
        Rl[idx] = R[(size_t)c * ODIM * NDIM + idx];
    __syncthreads();

    const int w    = tid >> 6;
    const int lane = tid & 63;
    const int r    = r0 + w;
    const float4 w4 = *(const float4*)(WcT + (size_t)r * NDIM + 4 * lane);

#pragma unroll
    for (int o = 0; o < ODIM; ++o) {
        const float* Ro = Rl + o * NDIM + 4 * lane;
        float p = fmaf(w4.x, Ro[0], fmaf(w4.y, Ro[1],
                  fmaf(w4.z, Ro[2], w4.w * Ro[3])));
#pragma unroll
        for (int m = 1; m < 64; m <<= 1) p += __shfl_xor(p, m);
        if (lane == o) weff[(size_t)r * ODIM + o] = p;
    }
}

// ---------------- fallback: single-wave sequential weff (r8/r9-verified) -----
__device__ __forceinline__ float wstep(float G[4], const float kp1[4],
                                       const float tk2[4], float tf) {
    const float dt = fast_rcp(tf);
    const float a  = 0.5f * dt;

    float e[4], al[4], rr[4], be[4];
#pragma unroll
    for (int j = 0; j < 4; ++j) {
        const float denom = fmaf(a, kp1[j], 1.0f);
        const float d     = fast_rcp(denom);
        const float ad    = a * d;
        e[j]  = fmaf(2.0f, d, -1.0f);
        al[j] = e[j] + ad;
        rr[j] = ad * tk2[j];
        be[j] = d * G[j];
    }

    float Ac = al[0], Bc = be[0];
#pragma unroll
    for (int j = 1; j < 4; ++j) { Bc = fmaf(al[j], Bc, be[j]); Ac *= al[j]; }

    SCAN_ROUND(0x111, 0xF)
    SCAN_ROUND(0x112, 0xF)
    SCAN_ROUND(0x114, 0xF)
    SCAN_ROUND(0x118, 0xF)
    SCAN_ROUND(0x142, 0xA)
    {
        const float Bp = dpp_fetch<0x143, 0xC>(Bc, 0.0f);
        Bc = fmaf(Ac, Bp, Bc);
    }

    float S = dpp_fetch<0x138, 0xF>(Bc, 0.0f);
#pragma unroll
    for (int j = 0; j < 4; ++j) {
        G[j] = fmaf(-rr[j], S, e[j] * G[j]);
        S    = fmaf(al[j], S, be[j]);
    }
    return dt * S;
}

__global__ __launch_bounds__(64) void weff_kernel(const float* __restrict__ mlp_w,
                                                  float* __restrict__ weff) {
    const int o    = blockIdx.x;
    const int lane = threadIdx.x;

    float kp1[4], tk2[4], G[4];
    init_kmaps(lane, kp1, tk2);
#pragma unroll
    for (int j = 0; j < 4; ++j) {
        const int k = 255 - (4 * lane + j);
        G[j] = sqrtf((float)(2 * k + 1)) * mlp_w[o * NDIM + k];
    }

    float tf = (float)T_STEPS;
#pragma unroll 2
    for (int t = T_STEPS; t >= 1; --t) {
        const float w = wstep(G, kp1, tk2, tf);
        if (lane == 63) weff[(t - 1) * ODIM + o] = w;
        tf -= 1.0f;
    }
}

// ---------------- contraction: out[b,o] = bias + sum_t f[t,b] weff[t,o] ------
__global__ __launch_bounds__(128) void partial_kernel(const float* __restrict__ f,
                                                      const float* __restrict__ weff,
                                                      float* __restrict__ part) {
    __shared__ float wsm[CHUNK * ODIM];
    const int tid = threadIdx.x;
    const int b   = blockIdx.x * 128 + tid;
    const int tc  = blockIdx.y;
    const int t0  = tc * CHUNK;

    for (int i = tid; i < CHUNK * ODIM; i += 128)
        wsm[i] = weff[t0 * ODIM + i];
    __syncthreads();

    float acc[ODIM];
#pragma unroll
    for (int o = 0; o < ODIM; ++o) acc[o] = 0.0f;

#pragma unroll 4
    for (int tt = 0; tt < CHUNK; ++tt) {
        const float fv = f[(t0 + tt) * BSZ + b];   // coalesced over b
#pragma unroll
        for (int o = 0; o < ODIM; ++o)
            acc[o] = fmaf(fv, wsm[tt * ODIM + o], acc[o]);
    }

#pragma unroll
    for (int o = 0; o < ODIM; ++o)
        part[(tc * BSZ + b) * ODIM + o] = acc[o];
}

__global__ __launch_bounds__(256) void reduce_kernel(const float* __restrict__ part,
                                                     const float* __restrict__ mlp_b,
                                                     float* __restrict__ out) {
    const int i = blockIdx.x * 256 + threadIdx.x;
    if (i >= BSZ * ODIM) return;
    const int o = i % ODIM;
    float s = mlp_b[o];
#pragma unroll
    for (int c = 0; c < NCHUNK; ++c) s += part[c * BSZ * ODIM + i];
    out[i] = s;
}

extern "C" void kernel_launch(void* const* d_in, const int* in_sizes, int n_in,
                              void* d_out, int out_size, void* d_ws, size_t ws_size,
                              hipStream_t stream) {
    const float* inputs = (const float*)d_in[0];  // [T=1024, B=512, 1]
    const float* mlp_w  = (const float*)d_in[1];  // [10, 256]
    const float* mlp_b  = (const float*)d_in[2];  // [10]
    float* out = (float*)d_out;                   // [512, 10]

    const size_t WcT_elems  = (size_t)T_STEPS * NDIM;         // 1 MB
    const size_t weff_elems = (size_t)T_STEPS * ODIM;
    const size_t part_elems = (size_t)NCHUNK * BSZ * ODIM;

    auto need = [&](int nch) {
        return ((size_t)nch * NDIM * NDIM + WcT_elems +
                (size_t)nch * ODIM * NDIM + weff_elems + part_elems) * sizeof(float);
    };

    if (ws_size >= need(16)) {
        constexpr int NCH = 16, V = 4, CT = T_STEPS / NCH;
        float* P    = (float*)d_ws;
        float* WcT  = P + (size_t)NCH * NDIM * NDIM;
        float* R    = WcT + WcT_elems;
        float* weff = R + (size_t)NCH * ODIM * NDIM;
        float* part = weff + weff_elems;
        chunk_kernel<NCH, V><<<dim3(NDIM / V, NCH), 64, 0, stream>>>(P, WcT);
        r_kernel<NCH><<<ODIM, 1024, 0, stream>>>(mlp_w, P, R);
        z_kernel<CT><<<T_STEPS / 4, 256, 0, stream>>>(WcT, R, weff);
        partial_kernel<<<dim3(BSZ / 128, NCHUNK), 128, 0, stream>>>(inputs, weff, part);
        reduce_kernel<<<(BSZ * ODIM + 255) / 256, 256, 0, stream>>>(part, mlp_b, out);
    } else if (ws_size >= need(8)) {
        constexpr int NCH = 8, V = 2, CT = T_STEPS / NCH;
        float* P    = (float*)d_ws;
        float* WcT  = P + (size_t)NCH * NDIM * NDIM;
        float* R    = WcT + WcT_elems;
        float* weff = R + (size_t)NCH * ODIM * NDIM;
        float* part = weff + weff_elems;
        chunk_kernel<NCH, V><<<dim3(NDIM / V, NCH), 64, 0, stream>>>(P, WcT);
        r_kernel<NCH><<<ODIM, 1024, 0, stream>>>(mlp_w, P, R);
        z_kernel<CT><<<T_STEPS / 4, 256, 0, stream>>>(WcT, R, weff);
        partial_kernel<<<dim3(BSZ / 128, NCHUNK), 128, 0, stream>>>(inputs, weff, part);
        reduce_kernel<<<(BSZ * ODIM + 255) / 256, 256, 0, stream>>>(part, mlp_b, out);
    } else {
        float* weff = (float*)d_ws;
        float* part = weff + weff_elems;
        weff_kernel<<<ODIM, 64, 0, stream>>>(mlp_w, weff);
        partial_kernel<<<dim3(BSZ / 128, NCHUNK), 128, 0, stream>>>(inputs, weff, part);
        reduce_kernel<<<(BSZ * ODIM + 255) / 256, 256, 0, stream>>>(part, mlp_b, out);
    }
}